// Round 3
// baseline (191.549 us; speedup 1.0000x reference)
//
#include <hip/hip_runtime.h>
#include <hip/hip_cooperative_groups.h>
#include <math.h>

namespace cg = cooperative_groups;

// EGARCH fused single cooperative kernel.
// Phase A: grid-stride f64 sum/sumsq partials -> grid.sync() -> redundant stats.
// Phase B: block-parallel constant-coefficient linear recurrence
//          (lh_t = beta*lh_{t-1} + c_t), warm-started WARM steps early
//          (beta^512 ~ 4e-12 << 0.1 threshold), then exp outputs.

constexpr int CHUNK   = 8192;           // outputs per chunk
constexpr int WARM    = 512;            // warm-up window
constexpr int DOM     = CHUNK + WARM;   // scan domain = 8704
constexpr int THREADS = 256;
constexpr int PER_THR = DOM / THREADS;  // 34 serial elements per thread
constexpr int STAGE_F = DOM + 4;        // staged floats (4-elem alignment shift)
constexpr int STAGE_F4 = STAGE_F / 4;   // 2177 float4 loads
constexpr int GRID    = 1024;           // 4 blocks/CU co-resident (LDS-limited)
constexpr float SQRT_2_OVER_PI = 0.7978845608028654f;

// LDS: buf (34832 B) + scratch (4096 B) = 38928 B -> 4 blocks/CU (155.7 KB/CU)
constexpr int SCRATCH_OFF = STAGE_F * 4;   // bytes

__global__ __launch_bounds__(THREADS, 4)
void egarch_fused(const float* __restrict__ r, int n, int nchunks,
                  const float* __restrict__ p_omega, const float* __restrict__ p_alpha,
                  const float* __restrict__ p_beta,  const float* __restrict__ p_gamma,
                  double* __restrict__ partial, float* __restrict__ out)
{
    __shared__ __align__(16) char smem[SCRATCH_OFF + 4096];
    float*  buf  = (float*)smem;                      // STAGE_F floats
    double* dsum = (double*)(smem + SCRATCH_OFF);     // 256 doubles
    double* dsq  = dsum + THREADS;                    // 256 doubles
    float*  sA0  = (float*)(smem + SCRATCH_OFF);      // aliased after stats consumed
    float*  sA1  = sA0 + THREADS;
    float*  sB0  = sA1 + THREADS;
    float*  sB1  = sB0 + THREADS;

    const int tid = threadIdx.x;
    const int bid = blockIdx.x;
    const int n4  = n >> 2;
    const float4* r4 = (const float4*)r;

    // ---------------- Phase A: partial sum / sumsq (f64, deterministic) --------
    double s = 0.0, q = 0.0;
    {
        int i = bid * THREADS + tid;
        const int stride = GRID * THREADS;
        #pragma unroll 4
        for (; i < n4; i += stride) {
            float4 v = r4[i];
            s += (double)v.x + (double)v.y + (double)v.z + (double)v.w;
            q += (double)v.x * (double)v.x + (double)v.y * (double)v.y
               + (double)v.z * (double)v.z + (double)v.w * (double)v.w;
        }
    }
    dsum[tid] = s; dsq[tid] = q;
    __syncthreads();
    for (int off = THREADS / 2; off > 0; off >>= 1) {
        if (tid < off) { dsum[tid] += dsum[tid + off]; dsq[tid] += dsq[tid + off]; }
        __syncthreads();
    }
    if (tid == 0) {
        partial[2 * bid]     = dsum[0];
        partial[2 * bid + 1] = dsq[0];
    }
    __threadfence();              // make partials device-visible before grid sync
    cg::this_grid().sync();

    // ---------------- Stats: every block reduces all partials ------------------
    s = 0.0; q = 0.0;
    for (int i = tid; i < GRID; i += THREADS) {
        s += partial[2 * i];
        q += partial[2 * i + 1];
    }
    __syncthreads();              // dsum/dsq free to reuse
    dsum[tid] = s; dsq[tid] = q;
    __syncthreads();
    for (int off = THREADS / 2; off > 0; off >>= 1) {
        if (tid < off) { dsum[tid] += dsum[tid + off]; dsq[tid] += dsq[tid + off]; }
        __syncthreads();
    }
    float inv_std, log_h0;
    {
        double dn   = (double)n;
        double mean = dsum[0] / dn;
        double var  = (dsq[0] - dsum[0] * mean) / (dn - 1.0);   // ddof=1
        double sd   = sqrt(var) + 1e-8;
        inv_std = (float)(1.0 / sd);
        log_h0  = (float)log(var);
    }
    __syncthreads();              // stats consumed into registers; scratch reusable

    const float omega = p_omega[0], alpha = p_alpha[0];
    const float beta  = p_beta[0],  gamma = p_gamma[0];
    const float oms = omega - alpha * SQRT_2_OVER_PI;

    float* __restrict__ out0 = out;
    float* __restrict__ out1 = out + n;

    // ---------------- Phase B: chunks bid, bid+GRID, ... -----------------------
    for (int c = bid; c < nchunks; c += GRID) {
        const int d0 = c * CHUNK - WARM;
        // buf[j] = returns[d0 - 4 + j]  (aligned float4 staging)
        const int f4base = (d0 - 4) >> 2;
        for (int k4 = tid; k4 < STAGE_F4; k4 += THREADS) {
            int fi = f4base + k4;
            float4 v;
            if (fi >= 0 && fi < n4) v = r4[fi];
            else                    v = make_float4(0.f, 0.f, 0.f, 0.f);
            *(float4*)&buf[4 * k4] = v;
        }
        __syncthreads();

        // Pass 1: per-thread affine composition over its 34 elements
        float A = 1.0f, B = 0.0f;
        const int k0 = tid * PER_THR;
        for (int k = k0; k < k0 + PER_THR; ++k) {
            int t = d0 + k;
            if (t >= 1 && t < n) {
                float zp = buf[k + 3] * inv_std;
                float cc = fmaf(alpha, fabsf(zp), fmaf(gamma, zp, oms));
                A *= beta;
                B = fmaf(beta, B, cc);
            }
        }
        sA0[tid] = A; sB0[tid] = B;
        __syncthreads();

        // Hillis-Steele inclusive scan of affine transforms (double-buffered)
        float* srcA = sA0; float* srcB = sB0;
        float* dstA = sA1; float* dstB = sB1;
        for (int off = 1; off < THREADS; off <<= 1) {
            float a = srcA[tid], bb = srcB[tid];
            if (tid >= off) {
                float ap = srcA[tid - off], bp = srcB[tid - off];
                bb = fmaf(a, bp, bb);
                a *= ap;
            }
            dstA[tid] = a; dstB[tid] = bb;
            __syncthreads();
            float* tA = srcA; srcA = dstA; dstA = tA;
            float* tB = srcB; srcB = dstB; dstB = tB;
        }
        const float init = (c == 0) ? log_h0 : 0.0f;
        float lh = (tid == 0) ? init
                              : fmaf(srcA[tid - 1], init, srcB[tid - 1]);

        // Pass 2: replay, storing lh(t) into buf[k+3] (thread-local region)
        for (int k = k0; k < k0 + PER_THR; ++k) {
            int t = d0 + k;
            if (t >= 1 && t < n) {
                float zp = buf[k + 3] * inv_std;
                float cc = fmaf(alpha, fabsf(zp), fmaf(gamma, zp, oms));
                lh = fmaf(beta, lh, cc);
            }
            buf[k + 3] = lh;   // t<=0 (chunk 0 warm-up): holds init at t=0
        }
        __syncthreads();

        // Coalesced float4 epilogue: out0 = exp(0.5*lh), out1 = exp(lh)
        for (int base = WARM + 4 * tid; base < DOM; base += 4 * THREADS) {
            int t = d0 + base;                  // multiple of 4
            if (t + 3 < n) {
                float l0 = buf[base + 3], l1 = buf[base + 4];
                float l2 = buf[base + 5], l3 = buf[base + 6];
                float4 e, h;
                e.x = __expf(0.5f * l0); e.y = __expf(0.5f * l1);
                e.z = __expf(0.5f * l2); e.w = __expf(0.5f * l3);
                h.x = __expf(l0); h.y = __expf(l1);
                h.z = __expf(l2); h.w = __expf(l3);
                *(float4*)&out0[t] = e;
                *(float4*)&out1[t] = h;
            } else {
                for (int j = 0; j < 4; ++j) {
                    int tt = t + j;
                    if (tt >= 0 && tt < n) {
                        float l = buf[base + 3 + j];
                        out0[tt] = __expf(0.5f * l);
                        out1[tt] = __expf(l);
                    }
                }
            }
        }
        __syncthreads();   // protect buf before next chunk's staging
    }
}

extern "C" void kernel_launch(void* const* d_in, const int* in_sizes, int n_in,
                              void* d_out, int out_size, void* d_ws, size_t ws_size,
                              hipStream_t stream)
{
    const float* returns = (const float*)d_in[0];
    const float* omega   = (const float*)d_in[1];
    const float* alpha   = (const float*)d_in[2];
    const float* beta    = (const float*)d_in[3];
    const float* gamma   = (const float*)d_in[4];
    int n = in_sizes[0];
    int nchunks = (n + CHUNK - 1) / CHUNK;

    double* partial = (double*)d_ws;          // GRID * 2 doubles
    float*  out     = (float*)d_out;

    void* args[] = { (void*)&returns, (void*)&n, (void*)&nchunks,
                     (void*)&omega, (void*)&alpha, (void*)&beta, (void*)&gamma,
                     (void*)&partial, (void*)&out };
    hipLaunchCooperativeKernel((const void*)egarch_fused,
                               dim3(GRID), dim3(THREADS), args, 0, stream);
}

// Round 4
// 56.292 us; speedup vs baseline: 3.4028x; 3.4028x over previous
//
#include <hip/hip_runtime.h>
#include <math.h>

// EGARCH, 3-kernel pipeline (fused cooperative version regressed 3x - reverted).
// K1 reduce: f64 sum/sumsq partials. K2 stats: var/std/log_h0. K3 scan:
// block-parallel recurrence lh_t = beta*lh_{t-1} + c_t, warm-started WARM
// steps early (beta^512 ~ 4e-12 << threshold), shuffle-based affine scan,
// exp outputs.

constexpr int CHUNK   = 8192;            // outputs per block
constexpr int WARM    = 512;             // warm-up window
constexpr int DOM     = CHUNK + WARM;    // scan domain = 8704
constexpr int STHREADS = 512;            // scan block: 8 waves
constexpr int PER_THR = DOM / STHREADS;  // 17 serial elements per thread (odd: bank-friendly)
constexpr int STAGE_F = DOM + 4;         // staged floats (4-elem alignment shift)
constexpr int STAGE_F4 = STAGE_F / 4;    // 2177 float4 loads
constexpr int RED_BLOCKS = 1024;
constexpr int RTHREADS = 512;
constexpr float SQRT_2_OVER_PI = 0.7978845608028654f;

// ---------- Kernel A: per-block partial sum / sumsq in double ----------
__global__ __launch_bounds__(RTHREADS, 8)
void egarch_reduce(const float* __restrict__ r, int n, double* __restrict__ partial)
{
    __shared__ double ssum[RTHREADS];
    __shared__ double ssq[RTHREADS];
    const int tid = threadIdx.x;
    const int n4 = n >> 2;
    const float4* r4 = (const float4*)r;
    double s = 0.0, q = 0.0;
    for (int i = blockIdx.x * RTHREADS + tid; i < n4; i += RED_BLOCKS * RTHREADS) {
        float4 v = r4[i];
        s += (double)v.x + (double)v.y + (double)v.z + (double)v.w;
        q += (double)v.x * (double)v.x + (double)v.y * (double)v.y
           + (double)v.z * (double)v.z + (double)v.w * (double)v.w;
    }
    ssum[tid] = s; ssq[tid] = q;
    __syncthreads();
    for (int off = RTHREADS / 2; off > 0; off >>= 1) {
        if (tid < off) { ssum[tid] += ssum[tid + off]; ssq[tid] += ssq[tid + off]; }
        __syncthreads();
    }
    if (tid == 0) {
        partial[2 * blockIdx.x]     = ssum[0];
        partial[2 * blockIdx.x + 1] = ssq[0];
    }
}

// ---------- Kernel B: finalize stats ----------
__global__ __launch_bounds__(RTHREADS)
void egarch_stats(const double* __restrict__ partial, int n, float* __restrict__ stats)
{
    __shared__ double ssum[RTHREADS];
    __shared__ double ssq[RTHREADS];
    const int tid = threadIdx.x;
    double s = 0.0, q = 0.0;
    for (int i = tid; i < RED_BLOCKS; i += RTHREADS) {
        s += partial[2 * i];
        q += partial[2 * i + 1];
    }
    ssum[tid] = s; ssq[tid] = q;
    __syncthreads();
    for (int off = RTHREADS / 2; off > 0; off >>= 1) {
        if (tid < off) { ssum[tid] += ssum[tid + off]; ssq[tid] += ssq[tid + off]; }
        __syncthreads();
    }
    if (tid == 0) {
        double dn = (double)n;
        double mean = ssum[0] / dn;
        double var = (ssq[0] - ssum[0] * mean) / (dn - 1.0);   // ddof=1
        double sd = sqrt(var) + 1e-8;
        stats[0] = (float)(1.0 / sd);   // inv_std
        stats[1] = (float)log(var);     // log_h0
    }
}

// ---------- Kernel C: block-parallel scan + exp outputs ----------
// 512 threads, LDS ~34.9 KB -> 4 blocks/CU * 8 waves = 32 waves/CU (100%).
__global__ __launch_bounds__(STHREADS, 8)
void egarch_scan(const float* __restrict__ r, int n,
                 const float* __restrict__ p_omega, const float* __restrict__ p_alpha,
                 const float* __restrict__ p_beta,  const float* __restrict__ p_gamma,
                 const float* __restrict__ stats, float* __restrict__ out)
{
    __shared__ float buf[STAGE_F];   // staged returns -> c_t -> lh
    __shared__ float wTA[8];         // per-wave affine totals
    __shared__ float wTB[8];

    const int tid  = threadIdx.x;
    const int lane = tid & 63;
    const int wid  = tid >> 6;
    const int c    = blockIdx.x;
    const int d0   = c * CHUNK - WARM;      // first recurrence position in domain
    // buf[j] = returns[d0 - 4 + j]  (aligned float4 staging; d0-4 divisible by 4)
    const int f4base = (d0 - 4) >> 2;
    const int n4 = n >> 2;
    const float4* r4 = (const float4*)r;
    for (int k4 = tid; k4 < STAGE_F4; k4 += STHREADS) {
        int fi = f4base + k4;
        float4 v;
        if (fi >= 0 && fi < n4) v = r4[fi];
        else                    v = make_float4(0.f, 0.f, 0.f, 0.f);
        *(float4*)&buf[4 * k4] = v;
    }
    const float inv_std = stats[0];
    const float log_h0  = stats[1];
    const float omega = p_omega[0], alpha = p_alpha[0];
    const float beta  = p_beta[0],  gamma = p_gamma[0];
    const float oms = omega - alpha * SQRT_2_OVER_PI;
    __syncthreads();

    // Pass 1: per-thread affine composition over its 17 elements.
    // Also overwrite buf[k+3] (returns[t-1]) with c_t for pass-2 replay.
    float A = 1.0f, B = 0.0f;
    const int k0 = tid * PER_THR;
    #pragma unroll
    for (int i = 0; i < PER_THR; ++i) {
        int k = k0 + i;
        int t = d0 + k;
        if (t >= 1 && t < n) {
            float zp = buf[k + 3] * inv_std;
            float cc = fmaf(alpha, fabsf(zp), fmaf(gamma, zp, oms));
            buf[k + 3] = cc;        // thread-local slot: safe read-then-write
            A *= beta;
            B = fmaf(beta, B, cc);
        }
    }

    // Wave-level inclusive scan of affine transforms via shuffles
    #pragma unroll
    for (int off = 1; off < 64; off <<= 1) {
        float ap = __shfl_up(A, off);
        float bp = __shfl_up(B, off);
        if (lane >= off) { B = fmaf(A, bp, B); A *= ap; }
    }
    if (lane == 63) { wTA[wid] = A; wTB[wid] = B; }
    __syncthreads();

    // Wave-exclusive prefix (uniform within wave; LDS broadcast reads)
    float PA = 1.0f, PB = 0.0f;
    for (int w = 0; w < wid; ++w) {
        float ta = wTA[w], tb = wTB[w];
        PB = fmaf(ta, PB, tb);
        PA *= ta;
    }
    // Previous thread's full inclusive transform, applied to init
    const float init = (c == 0) ? log_h0 : 0.0f;
    float Ap = __shfl_up(A, 1);
    float Bp = __shfl_up(B, 1);
    float FA, FB;
    if (lane == 0) { FA = PA;      FB = PB; }
    else           { FA = Ap * PA; FB = fmaf(Ap, PB, Bp); }
    float lh = fmaf(FA, init, FB);

    // Pass 2: replay from stored c_t, writing lh(t) into buf[k+3]
    #pragma unroll
    for (int i = 0; i < PER_THR; ++i) {
        int k = k0 + i;
        int t = d0 + k;
        if (t >= 1 && t < n) {
            lh = fmaf(beta, lh, buf[k + 3]);
        }
        buf[k + 3] = lh;   // t<=0 (chunk 0 warm-up): holds init at t=0
    }
    __syncthreads();

    // Coalesced float4 epilogue: out0 = exp(0.5*lh), out1 = exp(lh)
    float* __restrict__ out0 = out;
    float* __restrict__ out1 = out + n;
    for (int base = WARM + 4 * tid; base < DOM; base += 4 * STHREADS) {
        int t = d0 + base;                  // multiple of 4
        if (t + 3 < n) {
            float l0 = buf[base + 3], l1 = buf[base + 4];
            float l2 = buf[base + 5], l3 = buf[base + 6];
            float4 e, h;
            e.x = __expf(0.5f * l0); e.y = __expf(0.5f * l1);
            e.z = __expf(0.5f * l2); e.w = __expf(0.5f * l3);
            h.x = __expf(l0); h.y = __expf(l1);
            h.z = __expf(l2); h.w = __expf(l3);
            *(float4*)&out0[t] = e;
            *(float4*)&out1[t] = h;
        } else {
            for (int j = 0; j < 4; ++j) {
                int tt = t + j;
                if (tt >= 0 && tt < n) {
                    float l = buf[base + 3 + j];
                    out0[tt] = __expf(0.5f * l);
                    out1[tt] = __expf(l);
                }
            }
        }
    }
}

extern "C" void kernel_launch(void* const* d_in, const int* in_sizes, int n_in,
                              void* d_out, int out_size, void* d_ws, size_t ws_size,
                              hipStream_t stream)
{
    const float* returns = (const float*)d_in[0];
    const float* omega   = (const float*)d_in[1];
    const float* alpha   = (const float*)d_in[2];
    const float* beta    = (const float*)d_in[3];
    const float* gamma   = (const float*)d_in[4];
    const int n = in_sizes[0];

    double* partial = (double*)d_ws;                          // RED_BLOCKS * 2 doubles
    float*  stats   = (float*)((char*)d_ws + RED_BLOCKS * 2 * sizeof(double));

    float* out = (float*)d_out;

    egarch_reduce<<<RED_BLOCKS, RTHREADS, 0, stream>>>(returns, n, partial);
    egarch_stats<<<1, RTHREADS, 0, stream>>>(partial, n, stats);
    const int nblocks = (n + CHUNK - 1) / CHUNK;
    egarch_scan<<<nblocks, STHREADS, 0, stream>>>(returns, n, omega, alpha, beta, gamma,
                                                  stats, out);
}